// Round 8
// baseline (236.692 us; speedup 1.0000x reference)
//
#include <hip/hip_runtime.h>

typedef short short8 __attribute__((ext_vector_type(8)));
typedef float f32x4  __attribute__((ext_vector_type(4)));

#define TWO_N 8192
#define NHALF 4096
#define DDIM  256

__device__ __forceinline__ float b2f(unsigned short u) {
    return __uint_as_float(((unsigned int)u) << 16);
}
__device__ __forceinline__ unsigned short f2b(float f) {
    unsigned int u = __float_as_uint(f);
    u += 0x7fffu + ((u >> 16) & 1u);   // RNE; values are finite here
    return (unsigned short)(u >> 16);
}

// Runtime input-dtype probe (validated R4).
__device__ __forceinline__ int probe_is_f32(const void* p, int lane) {
    unsigned int u = ((const unsigned int*)p)[lane];
    float lowv = __uint_as_float(u << 16);
    int crazy = !(fabsf(lowv) <= 1024.0f);
    return __ballot(crazy) != 0ull;
}

// async global->LDS DMA, 16 B/lane, LDS dest = uniform base + lane*16
typedef __attribute__((address_space(1))) const unsigned int guint_t;
typedef __attribute__((address_space(3))) unsigned int luint_t;
__device__ __forceinline__ void gl_lds16(const unsigned short* g, unsigned short* l) {
    __builtin_amdgcn_global_load_lds((guint_t*)(const void*)g, (luint_t*)(void*)l, 16, 0, 0);
}

// ---- kernel 1: L2-normalize rows (fp32 math), write bf16 reps --------------
__global__ __launch_bounds__(256) void k_norm(const void* __restrict__ ei,
                                              const void* __restrict__ ej,
                                              unsigned short* __restrict__ reps) {
    int row  = (blockIdx.x * 256 + threadIdx.x) >> 6;   // one wave per row
    int lane = threadIdx.x & 63;
    int isf  = probe_is_f32(ei, lane);                  // wave-uniform
    int first = (row < NHALF);
    int r     = first ? row : row - NHALF;
    float x0, x1, x2, x3;
    if (isf) {
        const float* s = (first ? (const float*)ei : (const float*)ej) + (size_t)r * DDIM;
        float4 v = ((const float4*)s)[lane];
        x0 = v.x; x1 = v.y; x2 = v.z; x3 = v.w;
    } else {
        const unsigned short* s =
            (first ? (const unsigned short*)ei : (const unsigned short*)ej) + (size_t)r * DDIM;
        ushort4 v = ((const ushort4*)s)[lane];
        x0 = b2f(v.x); x1 = b2f(v.y); x2 = b2f(v.z); x3 = b2f(v.w);
    }
    float ss = x0 * x0 + x1 * x1 + x2 * x2 + x3 * x3;
    for (int off = 32; off > 0; off >>= 1) ss += __shfl_xor(ss, off);
    float inv = 1.0f / fmaxf(sqrtf(ss), 1e-12f);
    ushort4 o;
    o.x = f2b(x0 * inv); o.y = f2b(x1 * inv);
    o.z = f2b(x2 * inv); o.w = f2b(x3 * inv);
    ((ushort4*)(reps + (size_t)row * DDIM))[lane] = o;
}

// ---- kernel 2: upper-triangular 128x128 GEMM + exp row/col sums ------------
// Wave w owns rows w*32..+31 x all 128 cols. B double-buffered in LDS via
// global_load_lds + XOR chunk swizzle (conflict-free b128 reads). A comes
// from global per-chunk through a 1-deep register pipeline (a_cur/a_nxt,
// 16+16 VGPRs) -- R6/R7 held all of A (64 VGPRs, K-long live range) and the
// allocator spilled it to scratch: 505 MB HBM writes. Short live ranges fix it.
__global__ __launch_bounds__(256) void k_main(const unsigned short* __restrict__ R,
                                              float* __restrict__ S_row,
                                              float* __restrict__ S_col,
                                              float* __restrict__ pos) {
    __shared__ __align__(16) unsigned short Bs[2][128 * 64];   // 2 x 16 KB

    // decode blockIdx -> (rb, cb), rb <= cb (validated R5)
    int b = blockIdx.x;
    int rb = (int)((129.0f - sqrtf(16641.0f - 8.0f * (float)b)) * 0.5f);
    if (rb > 63) rb = 63;
    while ((129 * (rb + 1) - (rb + 1) * (rb + 1)) / 2 <= b) ++rb;
    while ((129 * rb - rb * rb) / 2 > b) --rb;
    int cb = rb + (b - (129 * rb - rb * rb) / 2);

    const int tid  = threadIdx.x;
    const int w    = tid >> 6;            // wave 0..3, owns rows w*32..+31
    const int lane = tid & 63;
    const int quad = lane >> 4;
    const int l16  = lane & 15;
    const int r8   = lane >> 3;           // staging: row within 8-row group
    const int c8   = (lane & 7) ^ r8;     // staging: swizzled 16B chunk

    const unsigned short* abase =
        R + (size_t)(rb * 128 + w * 32 + l16) * DDIM + quad * 8;
    const unsigned short* bbase = R + (size_t)(cb * 128) * DDIM;

    // ---- DMA B chunk 0; then prime A pipeline with chunk 0 ------------------
#pragma unroll
    for (int t = 0; t < 4; ++t) {
        int u = w * 4 + t;                // 8-row group 0..15
        gl_lds16(bbase + (size_t)(u * 8 + r8) * DDIM + c8 * 8, &Bs[0][u * 512]);
    }
    short8 a_cur[2][2];
#pragma unroll
    for (int rt = 0; rt < 2; ++rt)
#pragma unroll
        for (int kk = 0; kk < 2; ++kk)
            a_cur[rt][kk] = *(const short8*)(abase + rt * 16 * DDIM + kk * 32);

    f32x4 acc[2][8];
#pragma unroll
    for (int rt = 0; rt < 2; ++rt)
#pragma unroll
        for (int c = 0; c < 8; ++c) {
            acc[rt][c][0] = 0.0f; acc[rt][c][1] = 0.0f;
            acc[rt][c][2] = 0.0f; acc[rt][c][3] = 0.0f;
        }

#pragma unroll
    for (int kc = 0; kc < 4; ++kc) {      // K = 256 in chunks of 64
        __syncthreads();                  // B(kc) ready (drains DMA + A loads)
        if (kc < 3) {                     // DMA B(kc+1) into other buffer
#pragma unroll
            for (int t = 0; t < 4; ++t) {
                int u = w * 4 + t;
                gl_lds16(bbase + (size_t)(u * 8 + r8) * DDIM + (kc + 1) * 64 + c8 * 8,
                         &Bs[(kc + 1) & 1][u * 512]);
            }
        }
        short8 a_nxt[2][2];
        if (kc < 3) {                     // prefetch A chunk kc+1 (L2-warm)
#pragma unroll
            for (int rt = 0; rt < 2; ++rt)
#pragma unroll
                for (int kk = 0; kk < 2; ++kk)
                    a_nxt[rt][kk] = *(const short8*)(abase + rt * 16 * DDIM +
                                                     (kc + 1) * 64 + kk * 32);
        }
        const unsigned short* bsrc = Bs[kc & 1];
#pragma unroll
        for (int kk = 0; kk < 2; ++kk) {
            int q  = kk * 4 + quad;       // logical 16B chunk (k = q*8)
            int sl = q ^ (l16 & 7);       // physical slot after swizzle
            short8 bfr[8];
#pragma unroll
            for (int c = 0; c < 8; ++c)
                bfr[c] = *(const short8*)(&bsrc[(c * 16 + l16) * 64 + sl * 8]);
#pragma unroll
            for (int rt = 0; rt < 2; ++rt)
#pragma unroll
                for (int c = 0; c < 8; ++c)
                    acc[rt][c] = __builtin_amdgcn_mfma_f32_16x16x32_bf16(
                        a_cur[rt][kk], bfr[c], acc[rt][c], 0, 0, 0);
        }
        if (kc < 3) {
#pragma unroll
            for (int rt = 0; rt < 2; ++rt)
#pragma unroll
                for (int kk = 0; kk < 2; ++kk)
                    a_cur[rt][kk] = a_nxt[rt][kk];
        }
    }

    // ---- epilogue: e = exp(2*dot - 2); row sums + mirror col sums ----------
    // C/D layout: col = l16, row = quad*4 + j.
    float col_acc[8] = {0.f, 0.f, 0.f, 0.f, 0.f, 0.f, 0.f, 0.f};
#pragma unroll
    for (int rt = 0; rt < 2; ++rt)
#pragma unroll
        for (int j = 0; j < 4; ++j) {
            float s = 0.0f;
#pragma unroll
            for (int c = 0; c < 8; ++c) {
                float e = __expf(fmaf(acc[rt][c][j], 2.0f, -2.0f));
                s += e;
                col_acc[c] += e;
            }
            s += __shfl_xor(s, 1);
            s += __shfl_xor(s, 2);
            s += __shfl_xor(s, 4);
            s += __shfl_xor(s, 8);
            if (l16 == 0) {
                int row = rb * 128 + w * 32 + rt * 16 + quad * 4 + j;
                S_row[(size_t)cb * TWO_N + row] = s;
            }
        }
    if (rb != cb) {
#pragma unroll
        for (int c = 0; c < 8; ++c) {
            float s = col_acc[c];
            s += __shfl_xor(s, 16);
            s += __shfl_xor(s, 32);
            if (lane < 16) {
                int col = cb * 128 + c * 16 + lane;   // mirror row index
                S_col[(size_t)(rb * 4 + w) * TWO_N + col] = s;
            }
        }
    }
    // positive pairs: diagonal of blocks (rb, rb+32); logit = 2*dot
    if (cb == rb + 32) {
#pragma unroll
        for (int rt = 0; rt < 2; ++rt)
#pragma unroll
            for (int j = 0; j < 4; ++j)
                if (l16 == quad * 4 + j)
                    pos[rb * 128 + w * 32 + rt * 16 + l16] =
                        2.0f * acc[rt][w * 2 + rt][j];
    }
}

// ---- kernel 3: per-row log-denominator minus positive logit ----------------
__global__ __launch_bounds__(256) void k_rows(const float* __restrict__ S_row,
                                              const float* __restrict__ S_col,
                                              const float* __restrict__ pos,
                                              float* __restrict__ t_row) {
    int row = blockIdx.x * 256 + threadIdx.x;
    int t   = row >> 7;                   // row block 0..63
    float s = 0.0f;
    for (int c = t; c < 64; ++c)  s += S_row[(size_t)c * TWO_N + row];
    for (int q = 0; q < 4 * t; ++q) s += S_col[(size_t)q * TWO_N + row];
    float p = (row < NHALF) ? pos[row] : pos[row - NHALF];
    // remove self term exp(l_ii - 2) ~= 1; log_denom = 2 + log(S - 1)
    t_row[row] = 2.0f + logf(s - 1.0f) - p;
}

// ---- kernel 4: final mean, dual-encoded scalar store -----------------------
__global__ __launch_bounds__(1024) void k_fin(const float* __restrict__ t_row,
                                              unsigned int* __restrict__ out) {
    int tid = threadIdx.x;
    float local = 0.0f;
    for (int i = tid; i < TWO_N; i += 1024) local += t_row[i];
    __shared__ float red[16];
    for (int off = 32; off > 0; off >>= 1) local += __shfl_xor(local, off);
    if ((tid & 63) == 0) red[tid >> 6] = local;
    __syncthreads();
    if (tid == 0) {
        float v = 0.0f;
        for (int wv = 0; wv < 16; ++wv) v += red[wv];
        float L = v / 8192.0f;
        unsigned int bb = (unsigned int)f2b(L);
        out[0] = (bb << 16) | bb;   // bf16 in low half, ~f32(L) as full word
    }
}

// ---- launcher --------------------------------------------------------------
extern "C" void kernel_launch(void* const* d_in, const int* in_sizes, int n_in,
                              void* d_out, int out_size, void* d_ws, size_t ws_size,
                              hipStream_t stream) {
    (void)in_sizes; (void)n_in; (void)out_size; (void)ws_size;
    const void* ei = d_in[0];
    const void* ej = d_in[1];
    char* ws = (char*)d_ws;

    float*          pos   = (float*)(ws);                  // 4096 f32    (16 KB)
    float*          t_row = (float*)(ws + 16384);          // 8192 f32    (32 KB)
    unsigned short* reps  = (unsigned short*)(ws + 49152); // 8192x256    (4 MB)
    float*          S_row = (float*)(ws + 4243456);        // 64x8192 f32 (2 MB)
    float*          S_col = (float*)(ws + 6340608);        // 256x8192 f32 (8 MB)

    k_norm<<<2048, 256, 0, stream>>>(ei, ej, reps);
    k_main<<<2080, 256, 0, stream>>>(reps, S_row, S_col, pos);
    k_rows<<<32,   256, 0, stream>>>(S_row, S_col, pos, t_row);
    k_fin <<<1,   1024, 0, stream>>>(t_row, (unsigned int*)d_out);
}

// Round 9
// 164.238 us; speedup vs baseline: 1.4412x; 1.4412x over previous
//
#include <hip/hip_runtime.h>

typedef short short8 __attribute__((ext_vector_type(8)));
typedef float f32x4  __attribute__((ext_vector_type(4)));

#define TWO_N 8192
#define NHALF 4096
#define DDIM  256

__device__ __forceinline__ float b2f(unsigned short u) {
    return __uint_as_float(((unsigned int)u) << 16);
}
__device__ __forceinline__ unsigned short f2b(float f) {
    unsigned int u = __float_as_uint(f);
    u += 0x7fffu + ((u >> 16) & 1u);   // RNE; values are finite here
    return (unsigned short)(u >> 16);
}

// Runtime input-dtype probe (validated R4).
__device__ __forceinline__ int probe_is_f32(const void* p, int lane) {
    unsigned int u = ((const unsigned int*)p)[lane];
    float lowv = __uint_as_float(u << 16);
    int crazy = !(fabsf(lowv) <= 1024.0f);
    return __ballot(crazy) != 0ull;
}

// async global->LDS DMA, 16 B/lane, LDS dest = uniform base + lane*16
typedef __attribute__((address_space(1))) const unsigned int guint_t;
typedef __attribute__((address_space(3))) unsigned int luint_t;
__device__ __forceinline__ void gl_lds16(const unsigned short* g, unsigned short* l) {
    __builtin_amdgcn_global_load_lds((guint_t*)(const void*)g, (luint_t*)(void*)l, 16, 0, 0);
}

// ---- kernel 1: L2-normalize rows (fp32 math), write bf16 reps --------------
__global__ __launch_bounds__(256) void k_norm(const void* __restrict__ ei,
                                              const void* __restrict__ ej,
                                              unsigned short* __restrict__ reps) {
    int row  = (blockIdx.x * 256 + threadIdx.x) >> 6;   // one wave per row
    int lane = threadIdx.x & 63;
    int isf  = probe_is_f32(ei, lane);                  // wave-uniform
    int first = (row < NHALF);
    int r     = first ? row : row - NHALF;
    float x0, x1, x2, x3;
    if (isf) {
        const float* s = (first ? (const float*)ei : (const float*)ej) + (size_t)r * DDIM;
        float4 v = ((const float4*)s)[lane];
        x0 = v.x; x1 = v.y; x2 = v.z; x3 = v.w;
    } else {
        const unsigned short* s =
            (first ? (const unsigned short*)ei : (const unsigned short*)ej) + (size_t)r * DDIM;
        ushort4 v = ((const ushort4*)s)[lane];
        x0 = b2f(v.x); x1 = b2f(v.y); x2 = b2f(v.z); x3 = b2f(v.w);
    }
    float ss = x0 * x0 + x1 * x1 + x2 * x2 + x3 * x3;
    for (int off = 32; off > 0; off >>= 1) ss += __shfl_xor(ss, off);
    float inv = 1.0f / fmaxf(sqrtf(ss), 1e-12f);
    ushort4 o;
    o.x = f2b(x0 * inv); o.y = f2b(x1 * inv);
    o.z = f2b(x2 * inv); o.w = f2b(x3 * inv);
    ((ushort4*)(reps + (size_t)row * DDIM))[lane] = o;
}

// ---- kernel 2: upper-triangular 128x128 GEMM + exp row/col sums ------------
// Wave w owns rows w*32..+31 x all 128 cols. B double-buffered in LDS via
// global_load_lds + XOR chunk swizzle (conflict-free b128 reads); A through a
// 1-deep register pipeline. CRITICAL: every index into acc[][] must be a
// compile-time constant — R6/R7/R8 had `acc[rt][w*2+rt][j]` (runtime w) in the
// pos extraction, which demoted the whole accumulator array to scratch
// (~550 MB HBM spill writes/dispatch, MfmaUtil 6%). Predicated constant-index
// form keeps acc in VGPRs.
__global__ __launch_bounds__(256) void k_main(const unsigned short* __restrict__ R,
                                              float* __restrict__ S_row,
                                              float* __restrict__ S_col,
                                              float* __restrict__ pos) {
    __shared__ __align__(16) unsigned short Bs[2][128 * 64];   // 2 x 16 KB

    // decode blockIdx -> (rb, cb), rb <= cb (validated R5)
    int b = blockIdx.x;
    int rb = (int)((129.0f - sqrtf(16641.0f - 8.0f * (float)b)) * 0.5f);
    if (rb > 63) rb = 63;
    while ((129 * (rb + 1) - (rb + 1) * (rb + 1)) / 2 <= b) ++rb;
    while ((129 * rb - rb * rb) / 2 > b) --rb;
    int cb = rb + (b - (129 * rb - rb * rb) / 2);

    const int tid  = threadIdx.x;
    const int w    = tid >> 6;            // wave 0..3, owns rows w*32..+31
    const int lane = tid & 63;
    const int quad = lane >> 4;
    const int l16  = lane & 15;
    const int r8   = lane >> 3;           // staging: row within 8-row group
    const int c8   = (lane & 7) ^ r8;     // staging: swizzled 16B chunk

    const unsigned short* abase =
        R + (size_t)(rb * 128 + w * 32 + l16) * DDIM + quad * 8;
    const unsigned short* bbase = R + (size_t)(cb * 128) * DDIM;

    // ---- DMA B chunk 0; then prime A pipeline with chunk 0 ------------------
#pragma unroll
    for (int t = 0; t < 4; ++t) {
        int u = w * 4 + t;                // 8-row group 0..15
        gl_lds16(bbase + (size_t)(u * 8 + r8) * DDIM + c8 * 8, &Bs[0][u * 512]);
    }
    short8 a_cur[2][2];
#pragma unroll
    for (int rt = 0; rt < 2; ++rt)
#pragma unroll
        for (int kk = 0; kk < 2; ++kk)
            a_cur[rt][kk] = *(const short8*)(abase + rt * 16 * DDIM + kk * 32);

    f32x4 acc[2][8];
#pragma unroll
    for (int rt = 0; rt < 2; ++rt)
#pragma unroll
        for (int c = 0; c < 8; ++c) {
            acc[rt][c][0] = 0.0f; acc[rt][c][1] = 0.0f;
            acc[rt][c][2] = 0.0f; acc[rt][c][3] = 0.0f;
        }

#pragma unroll
    for (int kc = 0; kc < 4; ++kc) {      // K = 256 in chunks of 64
        __syncthreads();                  // B(kc) ready (drains DMA + A loads)
        if (kc < 3) {                     // DMA B(kc+1) into other buffer
#pragma unroll
            for (int t = 0; t < 4; ++t) {
                int u = w * 4 + t;
                gl_lds16(bbase + (size_t)(u * 8 + r8) * DDIM + (kc + 1) * 64 + c8 * 8,
                         &Bs[(kc + 1) & 1][u * 512]);
            }
        }
        short8 a_nxt[2][2];
        if (kc < 3) {                     // prefetch A chunk kc+1 (L2-warm)
#pragma unroll
            for (int rt = 0; rt < 2; ++rt)
#pragma unroll
                for (int kk = 0; kk < 2; ++kk)
                    a_nxt[rt][kk] = *(const short8*)(abase + rt * 16 * DDIM +
                                                     (kc + 1) * 64 + kk * 32);
        }
        const unsigned short* bsrc = Bs[kc & 1];
#pragma unroll
        for (int kk = 0; kk < 2; ++kk) {
            int q  = kk * 4 + quad;       // logical 16B chunk (k = q*8)
            int sl = q ^ (l16 & 7);       // physical slot after swizzle
            short8 bfr[8];
#pragma unroll
            for (int c = 0; c < 8; ++c)
                bfr[c] = *(const short8*)(&bsrc[(c * 16 + l16) * 64 + sl * 8]);
#pragma unroll
            for (int rt = 0; rt < 2; ++rt)
#pragma unroll
                for (int c = 0; c < 8; ++c)
                    acc[rt][c] = __builtin_amdgcn_mfma_f32_16x16x32_bf16(
                        a_cur[rt][kk], bfr[c], acc[rt][c], 0, 0, 0);
        }
        if (kc < 3) {
#pragma unroll
            for (int rt = 0; rt < 2; ++rt)
#pragma unroll
                for (int kk = 0; kk < 2; ++kk)
                    a_cur[rt][kk] = a_nxt[rt][kk];
        }
    }

    // ---- epilogue: e = exp(2*dot - 2); row sums + mirror col sums ----------
    // C/D layout: col = l16, row = quad*4 + j.
    float col_acc[8] = {0.f, 0.f, 0.f, 0.f, 0.f, 0.f, 0.f, 0.f};
#pragma unroll
    for (int rt = 0; rt < 2; ++rt)
#pragma unroll
        for (int j = 0; j < 4; ++j) {
            float s = 0.0f;
#pragma unroll
            for (int c = 0; c < 8; ++c) {
                float e = __expf(fmaf(acc[rt][c][j], 2.0f, -2.0f));
                s += e;
                col_acc[c] += e;
            }
            s += __shfl_xor(s, 1);
            s += __shfl_xor(s, 2);
            s += __shfl_xor(s, 4);
            s += __shfl_xor(s, 8);
            if (l16 == 0) {
                int row = rb * 128 + w * 32 + rt * 16 + quad * 4 + j;
                S_row[(size_t)cb * TWO_N + row] = s;
            }
        }
    if (rb != cb) {
#pragma unroll
        for (int c = 0; c < 8; ++c) {
            float s = col_acc[c];
            s += __shfl_xor(s, 16);
            s += __shfl_xor(s, 32);
            if (lane < 16) {
                int col = cb * 128 + c * 16 + lane;   // mirror row index
                S_col[(size_t)(rb * 4 + w) * TWO_N + col] = s;
            }
        }
    }
    // positive pairs: diagonal of blocks (rb, rb+32); logit = 2*dot.
    // ALL acc indices compile-time; runtime selection via predicate only.
    if (cb == rb + 32) {
#pragma unroll
        for (int rt = 0; rt < 2; ++rt)
#pragma unroll
            for (int c = 0; c < 8; ++c)
                if (c == w * 2 + rt) {
#pragma unroll
                    for (int j = 0; j < 4; ++j)
                        if (l16 == quad * 4 + j)
                            pos[rb * 128 + w * 32 + rt * 16 + l16] =
                                2.0f * acc[rt][c][j];
                }
    }
}

// ---- kernel 3: per-row log-denominator minus positive logit ----------------
__global__ __launch_bounds__(256) void k_rows(const float* __restrict__ S_row,
                                              const float* __restrict__ S_col,
                                              const float* __restrict__ pos,
                                              float* __restrict__ t_row) {
    int row = blockIdx.x * 256 + threadIdx.x;
    int t   = row >> 7;                   // row block 0..63
    float s = 0.0f;
    for (int c = t; c < 64; ++c)  s += S_row[(size_t)c * TWO_N + row];
    for (int q = 0; q < 4 * t; ++q) s += S_col[(size_t)q * TWO_N + row];
    float p = (row < NHALF) ? pos[row] : pos[row - NHALF];
    // remove self term exp(l_ii - 2) ~= 1; log_denom = 2 + log(S - 1)
    t_row[row] = 2.0f + logf(s - 1.0f) - p;
}

// ---- kernel 4: final mean, dual-encoded scalar store -----------------------
__global__ __launch_bounds__(1024) void k_fin(const float* __restrict__ t_row,
                                              unsigned int* __restrict__ out) {
    int tid = threadIdx.x;
    float local = 0.0f;
    for (int i = tid; i < TWO_N; i += 1024) local += t_row[i];
    __shared__ float red[16];
    for (int off = 32; off > 0; off >>= 1) local += __shfl_xor(local, off);
    if ((tid & 63) == 0) red[tid >> 6] = local;
    __syncthreads();
    if (tid == 0) {
        float v = 0.0f;
        for (int wv = 0; wv < 16; ++wv) v += red[wv];
        float L = v / 8192.0f;
        unsigned int bb = (unsigned int)f2b(L);
        out[0] = (bb << 16) | bb;   // bf16 in low half, ~f32(L) as full word
    }
}

// ---- launcher --------------------------------------------------------------
extern "C" void kernel_launch(void* const* d_in, const int* in_sizes, int n_in,
                              void* d_out, int out_size, void* d_ws, size_t ws_size,
                              hipStream_t stream) {
    (void)in_sizes; (void)n_in; (void)out_size; (void)ws_size;
    const void* ei = d_in[0];
    const void* ej = d_in[1];
    char* ws = (char*)d_ws;

    float*          pos   = (float*)(ws);                  // 4096 f32    (16 KB)
    float*          t_row = (float*)(ws + 16384);          // 8192 f32    (32 KB)
    unsigned short* reps  = (unsigned short*)(ws + 49152); // 8192x256    (4 MB)
    float*          S_row = (float*)(ws + 4243456);        // 64x8192 f32 (2 MB)
    float*          S_col = (float*)(ws + 6340608);        // 256x8192 f32 (8 MB)

    k_norm<<<2048, 256, 0, stream>>>(ei, ej, reps);
    k_main<<<2080, 256, 0, stream>>>(reps, S_row, S_col, pos);
    k_rows<<<32,   256, 0, stream>>>(S_row, S_col, pos, t_row);
    k_fin <<<1,   1024, 0, stream>>>(t_row, (unsigned int*)d_out);
}

// Round 10
// 119.313 us; speedup vs baseline: 1.9838x; 1.3765x over previous
//
#include <hip/hip_runtime.h>

typedef short short8 __attribute__((ext_vector_type(8)));
typedef float f32x4  __attribute__((ext_vector_type(4)));

#define TWO_N 8192
#define NHALF 4096
#define DDIM  256

__device__ __forceinline__ float b2f(unsigned short u) {
    return __uint_as_float(((unsigned int)u) << 16);
}
__device__ __forceinline__ unsigned short f2b(float f) {
    unsigned int u = __float_as_uint(f);
    u += 0x7fffu + ((u >> 16) & 1u);   // RNE; values are finite here
    return (unsigned short)(u >> 16);
}

// Runtime input-dtype probe (validated R4).
__device__ __forceinline__ int probe_is_f32(const void* p, int lane) {
    unsigned int u = ((const unsigned int*)p)[lane];
    float lowv = __uint_as_float(u << 16);
    int crazy = !(fabsf(lowv) <= 1024.0f);
    return __ballot(crazy) != 0ull;
}

// async global->LDS DMA, 16 B/lane, LDS dest = uniform base + lane*16
typedef __attribute__((address_space(1))) const unsigned int guint_t;
typedef __attribute__((address_space(3))) unsigned int luint_t;
__device__ __forceinline__ void gl_lds16(const unsigned short* g, unsigned short* l) {
    __builtin_amdgcn_global_load_lds((guint_t*)(const void*)g, (luint_t*)(void*)l, 16, 0, 0);
}

// ---- kernel 1: L2-normalize rows (fp32 math), write bf16 reps --------------
__global__ __launch_bounds__(256) void k_norm(const void* __restrict__ ei,
                                              const void* __restrict__ ej,
                                              unsigned short* __restrict__ reps) {
    int row  = (blockIdx.x * 256 + threadIdx.x) >> 6;   // one wave per row
    int lane = threadIdx.x & 63;
    int isf  = probe_is_f32(ei, lane);                  // wave-uniform
    int first = (row < NHALF);
    int r     = first ? row : row - NHALF;
    float x0, x1, x2, x3;
    if (isf) {
        const float* s = (first ? (const float*)ei : (const float*)ej) + (size_t)r * DDIM;
        float4 v = ((const float4*)s)[lane];
        x0 = v.x; x1 = v.y; x2 = v.z; x3 = v.w;
    } else {
        const unsigned short* s =
            (first ? (const unsigned short*)ei : (const unsigned short*)ej) + (size_t)r * DDIM;
        ushort4 v = ((const ushort4*)s)[lane];
        x0 = b2f(v.x); x1 = b2f(v.y); x2 = b2f(v.z); x3 = b2f(v.w);
    }
    float ss = x0 * x0 + x1 * x1 + x2 * x2 + x3 * x3;
    for (int off = 32; off > 0; off >>= 1) ss += __shfl_xor(ss, off);
    float inv = 1.0f / fmaxf(sqrtf(ss), 1e-12f);
    ushort4 o;
    o.x = f2b(x0 * inv); o.y = f2b(x1 * inv);
    o.z = f2b(x2 * inv); o.w = f2b(x3 * inv);
    ((ushort4*)(reps + (size_t)row * DDIM))[lane] = o;
}

// ---- kernel 2: upper-triangular 128x128 GEMM + exp row/col sums ------------
// (unchanged from R9 — spill-free, verified absmax 0.0. All acc[][] indices
// compile-time constant; runtime selection by predicate only.)
__global__ __launch_bounds__(256) void k_main(const unsigned short* __restrict__ R,
                                              float* __restrict__ S_row,
                                              float* __restrict__ S_col,
                                              float* __restrict__ pos) {
    __shared__ __align__(16) unsigned short Bs[2][128 * 64];   // 2 x 16 KB

    // decode blockIdx -> (rb, cb), rb <= cb (validated R5)
    int b = blockIdx.x;
    int rb = (int)((129.0f - sqrtf(16641.0f - 8.0f * (float)b)) * 0.5f);
    if (rb > 63) rb = 63;
    while ((129 * (rb + 1) - (rb + 1) * (rb + 1)) / 2 <= b) ++rb;
    while ((129 * rb - rb * rb) / 2 > b) --rb;
    int cb = rb + (b - (129 * rb - rb * rb) / 2);

    const int tid  = threadIdx.x;
    const int w    = tid >> 6;            // wave 0..3, owns rows w*32..+31
    const int lane = tid & 63;
    const int quad = lane >> 4;
    const int l16  = lane & 15;
    const int r8   = lane >> 3;           // staging: row within 8-row group
    const int c8   = (lane & 7) ^ r8;     // staging: swizzled 16B chunk

    const unsigned short* abase =
        R + (size_t)(rb * 128 + w * 32 + l16) * DDIM + quad * 8;
    const unsigned short* bbase = R + (size_t)(cb * 128) * DDIM;

    // ---- DMA B chunk 0; then prime A pipeline with chunk 0 ------------------
#pragma unroll
    for (int t = 0; t < 4; ++t) {
        int u = w * 4 + t;                // 8-row group 0..15
        gl_lds16(bbase + (size_t)(u * 8 + r8) * DDIM + c8 * 8, &Bs[0][u * 512]);
    }
    short8 a_cur[2][2];
#pragma unroll
    for (int rt = 0; rt < 2; ++rt)
#pragma unroll
        for (int kk = 0; kk < 2; ++kk)
            a_cur[rt][kk] = *(const short8*)(abase + rt * 16 * DDIM + kk * 32);

    f32x4 acc[2][8];
#pragma unroll
    for (int rt = 0; rt < 2; ++rt)
#pragma unroll
        for (int c = 0; c < 8; ++c) {
            acc[rt][c][0] = 0.0f; acc[rt][c][1] = 0.0f;
            acc[rt][c][2] = 0.0f; acc[rt][c][3] = 0.0f;
        }

#pragma unroll
    for (int kc = 0; kc < 4; ++kc) {      // K = 256 in chunks of 64
        __syncthreads();                  // B(kc) ready (drains DMA + A loads)
        if (kc < 3) {                     // DMA B(kc+1) into other buffer
#pragma unroll
            for (int t = 0; t < 4; ++t) {
                int u = w * 4 + t;
                gl_lds16(bbase + (size_t)(u * 8 + r8) * DDIM + (kc + 1) * 64 + c8 * 8,
                         &Bs[(kc + 1) & 1][u * 512]);
            }
        }
        short8 a_nxt[2][2];
        if (kc < 3) {                     // prefetch A chunk kc+1 (L2-warm)
#pragma unroll
            for (int rt = 0; rt < 2; ++rt)
#pragma unroll
                for (int kk = 0; kk < 2; ++kk)
                    a_nxt[rt][kk] = *(const short8*)(abase + rt * 16 * DDIM +
                                                     (kc + 1) * 64 + kk * 32);
        }
        const unsigned short* bsrc = Bs[kc & 1];
#pragma unroll
        for (int kk = 0; kk < 2; ++kk) {
            int q  = kk * 4 + quad;       // logical 16B chunk (k = q*8)
            int sl = q ^ (l16 & 7);       // physical slot after swizzle
            short8 bfr[8];
#pragma unroll
            for (int c = 0; c < 8; ++c)
                bfr[c] = *(const short8*)(&bsrc[(c * 16 + l16) * 64 + sl * 8]);
#pragma unroll
            for (int rt = 0; rt < 2; ++rt)
#pragma unroll
                for (int c = 0; c < 8; ++c)
                    acc[rt][c] = __builtin_amdgcn_mfma_f32_16x16x32_bf16(
                        a_cur[rt][kk], bfr[c], acc[rt][c], 0, 0, 0);
        }
        if (kc < 3) {
#pragma unroll
            for (int rt = 0; rt < 2; ++rt)
#pragma unroll
                for (int kk = 0; kk < 2; ++kk)
                    a_cur[rt][kk] = a_nxt[rt][kk];
        }
    }

    // ---- epilogue: e = exp(2*dot - 2); row sums + mirror col sums ----------
    float col_acc[8] = {0.f, 0.f, 0.f, 0.f, 0.f, 0.f, 0.f, 0.f};
#pragma unroll
    for (int rt = 0; rt < 2; ++rt)
#pragma unroll
        for (int j = 0; j < 4; ++j) {
            float s = 0.0f;
#pragma unroll
            for (int c = 0; c < 8; ++c) {
                float e = __expf(fmaf(acc[rt][c][j], 2.0f, -2.0f));
                s += e;
                col_acc[c] += e;
            }
            s += __shfl_xor(s, 1);
            s += __shfl_xor(s, 2);
            s += __shfl_xor(s, 4);
            s += __shfl_xor(s, 8);
            if (l16 == 0) {
                int row = rb * 128 + w * 32 + rt * 16 + quad * 4 + j;
                S_row[(size_t)cb * TWO_N + row] = s;
            }
        }
    if (rb != cb) {
#pragma unroll
        for (int c = 0; c < 8; ++c) {
            float s = col_acc[c];
            s += __shfl_xor(s, 16);
            s += __shfl_xor(s, 32);
            if (lane < 16) {
                int col = cb * 128 + c * 16 + lane;   // mirror row index
                S_col[(size_t)(rb * 4 + w) * TWO_N + col] = s;
            }
        }
    }
    // positive pairs: diagonal of blocks (rb, rb+32); logit = 2*dot.
    if (cb == rb + 32) {
#pragma unroll
        for (int rt = 0; rt < 2; ++rt)
#pragma unroll
            for (int c = 0; c < 8; ++c)
                if (c == w * 2 + rt) {
#pragma unroll
                    for (int j = 0; j < 4; ++j)
                        if (l16 == quad * 4 + j)
                            pos[rb * 128 + w * 32 + rt * 16 + l16] =
                                2.0f * acc[rt][c][j];
                }
    }
}

// ---- kernel 3: per-row log-denom minus pos, block-level partial sums -------
// R9's version was latency-starved (32 blocks, 158 serial scattered loads per
// thread -> 61.8 us at 0.8% occupancy). Now: 128 blocks x 256 thr; block owns
// 64 rows; wave w covers c = w (mod 4); LDS-reduce; wave 0 does log + 64-row
// shuffle-reduce -> one scalar per block.
__global__ __launch_bounds__(256) void k_rows(const float* __restrict__ S_row,
                                              const float* __restrict__ S_col,
                                              const float* __restrict__ pos,
                                              float* __restrict__ t_blk) {
    __shared__ float sm[4][64];
    const int tid  = threadIdx.x;
    const int w    = tid >> 6;            // c-split 0..3
    const int rin  = tid & 63;            // row within block's 64-row group
    const int row  = blockIdx.x * 64 + rin;
    const int t    = row >> 7;            // 128-row block index (uniform/block)

    float s = 0.0f;
    for (int c = t + w; c < 64; c += 4)   s += S_row[(size_t)c * TWO_N + row];
    for (int q = w; q < 4 * t; q += 4)    s += S_col[(size_t)q * TWO_N + row];
    sm[w][rin] = s;
    __syncthreads();
    if (w == 0) {
        float tot = sm[0][rin] + sm[1][rin] + sm[2][rin] + sm[3][rin];
        float p = (row < NHALF) ? pos[row] : pos[row - NHALF];
        // remove self term exp(l_ii - 2) ~= 1; log_denom = 2 + log(S - 1)
        float v = 2.0f + logf(tot - 1.0f) - p;
        for (int off = 32; off > 0; off >>= 1) v += __shfl_xor(v, off);
        if (rin == 0) t_blk[blockIdx.x] = v;
    }
}

// ---- kernel 4: final mean over 128 block sums, dual-encoded store ----------
__global__ __launch_bounds__(128) void k_fin(const float* __restrict__ t_blk,
                                             unsigned int* __restrict__ out) {
    int tid = threadIdx.x;
    float local = t_blk[tid];
    __shared__ float red[2];
    for (int off = 32; off > 0; off >>= 1) local += __shfl_xor(local, off);
    if ((tid & 63) == 0) red[tid >> 6] = local;
    __syncthreads();
    if (tid == 0) {
        float L = (red[0] + red[1]) / 8192.0f;
        unsigned int bb = (unsigned int)f2b(L);
        out[0] = (bb << 16) | bb;   // bf16 in low half, ~f32(L) as full word
    }
}

// ---- launcher --------------------------------------------------------------
extern "C" void kernel_launch(void* const* d_in, const int* in_sizes, int n_in,
                              void* d_out, int out_size, void* d_ws, size_t ws_size,
                              hipStream_t stream) {
    (void)in_sizes; (void)n_in; (void)out_size; (void)ws_size;
    const void* ei = d_in[0];
    const void* ej = d_in[1];
    char* ws = (char*)d_ws;

    float*          pos   = (float*)(ws);                  // 4096 f32    (16 KB)
    float*          t_blk = (float*)(ws + 16384);          // 128 f32
    unsigned short* reps  = (unsigned short*)(ws + 49152); // 8192x256    (4 MB)
    float*          S_row = (float*)(ws + 4243456);        // 64x8192 f32 (2 MB)
    float*          S_col = (float*)(ws + 6340608);        // 256x8192 f32 (8 MB)

    k_norm<<<2048, 256, 0, stream>>>(ei, ej, reps);
    k_main<<<2080, 256, 0, stream>>>(reps, S_row, S_col, pos);
    k_rows<<<128,  256, 0, stream>>>(S_row, S_col, pos, t_blk);
    k_fin <<<1,    128, 0, stream>>>(t_blk, (unsigned int*)d_out);
}